// Round 9
// baseline (379.217 us; speedup 1.0000x reference)
//
#include <hip/hip_runtime.h>
#include <hip/hip_bf16.h>

typedef __attribute__((ext_vector_type(8))) short short8;
typedef __attribute__((ext_vector_type(4))) float f32x4;

#define BB 16
#define VV 3
#define NN 512
#define SS 5
#define TT 32
#define DTDX 0.1f

#define GLOAD_LDS16(g, l)                                          \
  __builtin_amdgcn_global_load_lds(                                \
      (const __attribute__((address_space(1))) void*)(g),          \
      (__attribute__((address_space(3))) void*)(l), 16, 0, 0)

__device__ __forceinline__ float fast_tanh(float x) {
  float xc = fminf(fmaxf(x, -9.f), 9.f);
  float e = __expf(2.f * xc);
  return (e - 1.f) * __builtin_amdgcn_rcpf(e + 1.f);
}

__device__ __forceinline__ short f2bf(float x) {
  __hip_bfloat16 h = __float2bfloat16(x);
  return __builtin_bit_cast(short, h);
}

// ---------------- init: weight repack ----------------
// All weights in the verified 16x16x32 fragment format:
//   frag(nt, ks, lane): col = nt*16 + (lane&15), k = ks*32 + (lane>>4)*8 + q
// W2F: [32 nt][16 ks] frags (512 KB)
// W3F: [1 nt][16 ks] frags, cols>=5 zero (16 KB)
// W1F: [32 nt][1 ks] frags (32 KB); k<15 -> W1[k][col], k==15 -> b1[col]
__global__ void init_repack(const float* __restrict__ W1,
                            const float* __restrict__ b1,
                            const float* __restrict__ W2,
                            const float* __restrict__ W3,
                            short* __restrict__ W1F,
                            short* __restrict__ W2F,
                            short* __restrict__ W3F) {
  const int blk = blockIdx.x;
  const int tid = threadIdx.x;
  if (blk < 128) {
    const int fid = blk * 256 + tid;
    const int lane = fid & 63;
    const int rest = fid >> 6;
    const int ks = rest & 15;
    const int ct = rest >> 4;
    const int col = ct * 16 + (lane & 15);
    const int k0 = ks * 32 + (lane >> 4) * 8;
    short8 v;
#pragma unroll
    for (int q = 0; q < 8; ++q) v[q] = f2bf(W2[(size_t)(k0 + q) * 512 + col]);
    *(short8*)(W2F + (size_t)fid * 8) = v;
  } else if (blk < 132) {
    const int fid = (blk - 128) * 256 + tid;
    const int lane = fid & 63;
    const int ks = fid >> 6;
    const int ml = lane & 15;
    const int k0 = ks * 32 + (lane >> 4) * 8;
    short8 v;
#pragma unroll
    for (int q = 0; q < 8; ++q)
      v[q] = f2bf((ml < 5) ? W3[(size_t)(k0 + q) * 5 + ml] : 0.f);
    *(short8*)(W3F + (size_t)fid * 8) = v;
  } else {
    // W1F: 2048 fragments
    for (int fid = tid; fid < 2048; fid += 256) {
      const int lane = fid & 63;
      const int nt = fid >> 6;
      const int col = nt * 16 + (lane & 15);
      const int k0 = (lane >> 4) * 8;
      short8 v;
#pragma unroll
      for (int q = 0; q < 8; ++q) {
        const int k = k0 + q;
        float x = 0.f;
        if (k < 15) x = W1[(size_t)k * 512 + col];
        else if (k == 15) x = b1[col];
        v[q] = f2bf(x);
      }
      *(short8*)(W1F + (size_t)fid * 8) = v;
    }
  }
}

// ---------------- per-step fused cell ----------------
// Block = (batch b, 32-row chunk n0), 1024 threads = 16 waves.
// W2 staged via global_load_lds 3-slot ring w/ counted vmcnt (R7 proven).
// GEMM1 & GEMM3 via MFMA; B3 spread over all 16 waves (partial-sum reduce).
template <bool FIRST>
__global__ __launch_bounds__(1024, 4) void step_kernel(
    const float* __restrict__ u_prev, const float* __restrict__ flux_prev,
    const short* __restrict__ W1F, const short* __restrict__ W2F,
    const float* __restrict__ b2, const short* __restrict__ W3F,
    const float* __restrict__ b3, float* __restrict__ u_out,
    float* __restrict__ states_out, float* __restrict__ flux_out,
    float* __restrict__ actions_out, float* __restrict__ rewards_out) {
  __shared__ float u_lds[VV][40];
  __shared__ __align__(16) short h_lds[32 * 512];      // bf16, XOR-swizzled
  __shared__ __align__(16) short ring[16 * 3 * 1024];  // per-wave B ring, 96KB
  __shared__ float part_lds[8][32][6];                 // B3 partials (6KB)

  const int tid = threadIdx.x;
  const int blk = blockIdx.x;
  const int b = blk >> 4;
  const int n0 = (blk & 15) << 5;

  const int lane = tid & 63;
  const int wv = tid >> 6;
  const int ml = lane & 15;
  const int gg = lane >> 4;
  const int aswz = ml << 3;
  const int ct0 = wv * 2;
  short* const rb = ring + wv * 3072;

#define ISSUE_SLOT(ks2)                                                       \
  do {                                                                        \
    const int _s = (ks2) % 3;                                                 \
    GLOAD_LDS16(W2F + ((size_t)(ct0 * 16 + (ks2)) * 64 + lane) * 8,           \
                rb + _s * 1024);                                              \
    GLOAD_LDS16(W2F + ((size_t)((ct0 + 1) * 16 + (ks2)) * 64 + lane) * 8,     \
                rb + _s * 1024 + 512);                                        \
  } while (0)

  // prefetch first two ring slots; they complete during Phase A + B1
  ISSUE_SLOT(0);
  ISSUE_SLOT(1);

  // hoist W1F fragment loads: L2 latency hides under Phase A
  const short8 wb0 = *(const short8*)(W1F + ((size_t)ct0 * 64 + lane) * 8);
  const short8 wb1 =
      *(const short8*)(W1F + ((size_t)(ct0 + 1) * 64 + lane) * 8);

  // ---- Phase A: state update / load ----
  if (tid < 108) {
    const int v = tid / 36;
    const int i = tid - v * 36;
    const int n = (n0 - 2 + i) & (NN - 1);
    const int base = (b * VV + v) * NN;
    const int gi = base + n;
    float uv;
    if (FIRST) {
      uv = u_prev[gi];
    } else {
      const int nm = (n - 1) & (NN - 1);
      uv = u_prev[gi] - DTDX * (flux_prev[base + n] - flux_prev[base + nm]);
      if (i >= 2 && i < 34) {
        u_out[gi] = uv;
        __builtin_nontemporal_store(uv, states_out + gi);
      }
    }
    u_lds[v][i] = uv;
  }
  __syncthreads();  // drains vmcnt(0): prefetched slots resident

  // ---- B1: h1 = tanh(feats @ W1) via MFMA; K=32 (k=15 carries bias) ----
  {
    short8 afr[2];
#pragma unroll
    for (int mt = 0; mt < 2; ++mt) {
      const int r = mt * 16 + ml;
      short8 a;
#pragma unroll
      for (int q = 0; q < 8; ++q) a[q] = 0;
      if (gg == 0) {
#pragma unroll
        for (int q = 0; q < 8; ++q) {  // k = 0..7
          const int v = q / 5, s = q % 5;
          a[q] = f2bf(u_lds[v][r + s]);
        }
      } else if (gg == 1) {
#pragma unroll
        for (int q = 0; q < 7; ++q) {  // k = 8..14
          const int k = 8 + q;
          const int v = k / 5, s = k % 5;
          a[q] = f2bf(u_lds[v][r + s]);
        }
        a[7] = f2bf(1.0f);  // bias row (k=15)
      }
      afr[mt] = a;
    }
    f32x4 c[2][2];
#pragma unroll
    for (int mt = 0; mt < 2; ++mt)
#pragma unroll
      for (int nt = 0; nt < 2; ++nt) c[mt][nt] = (f32x4){0.f, 0.f, 0.f, 0.f};
    c[0][0] = __builtin_amdgcn_mfma_f32_16x16x32_bf16(afr[0], wb0, c[0][0], 0, 0, 0);
    c[1][0] = __builtin_amdgcn_mfma_f32_16x16x32_bf16(afr[1], wb0, c[1][0], 0, 0, 0);
    c[0][1] = __builtin_amdgcn_mfma_f32_16x16x32_bf16(afr[0], wb1, c[0][1], 0, 0, 0);
    c[1][1] = __builtin_amdgcn_mfma_f32_16x16x32_bf16(afr[1], wb1, c[1][1], 0, 0, 0);
#pragma unroll
    for (int nt = 0; nt < 2; ++nt) {
      const int col = (ct0 + nt) * 16 + ml;
#pragma unroll
      for (int mt = 0; mt < 2; ++mt) {
#pragma unroll
        for (int r = 0; r < 4; ++r) {
          const int row = mt * 16 + gg * 4 + r;
          h_lds[row * 512 + (col ^ ((row & 15) << 3))] =
              f2bf(fast_tanh(c[mt][nt][r]));
        }
      }
    }
  }
  __syncthreads();

  // ---- Phase B2: h2 = tanh(h1 @ W2 + b2); B staged via global_load_lds ----
  f32x4 acc[2][2];
#pragma unroll
  for (int mt = 0; mt < 2; ++mt)
#pragma unroll
    for (int nt = 0; nt < 2; ++nt) acc[mt][nt] = (f32x4){0.f, 0.f, 0.f, 0.f};

#pragma unroll
  for (int ks = 0; ks < 16; ++ks) {
    if (ks < 14) {
      ISSUE_SLOT(ks + 2);
      asm volatile("s_waitcnt vmcnt(4)" ::: "memory");
    } else if (ks == 14) {
      asm volatile("s_waitcnt vmcnt(2)" ::: "memory");
    } else {
      asm volatile("s_waitcnt vmcnt(0)" ::: "memory");
    }
    const int slot = ks % 3;
    const int k = ks * 32 + gg * 8;
    const short8 a0 = *(const short8*)(&h_lds[ml * 512 + (k ^ aswz)]);
    const short8 a1 = *(const short8*)(&h_lds[(16 + ml) * 512 + (k ^ aswz)]);
    const short8 b0 = *(const short8*)(rb + slot * 1024 + lane * 8);
    const short8 b1v = *(const short8*)(rb + slot * 1024 + 512 + lane * 8);
    __builtin_amdgcn_s_setprio(1);
    acc[0][0] = __builtin_amdgcn_mfma_f32_16x16x32_bf16(a0, b0, acc[0][0], 0, 0, 0);
    acc[1][0] = __builtin_amdgcn_mfma_f32_16x16x32_bf16(a1, b0, acc[1][0], 0, 0, 0);
    acc[0][1] = __builtin_amdgcn_mfma_f32_16x16x32_bf16(a0, b1v, acc[0][1], 0, 0, 0);
    acc[1][1] = __builtin_amdgcn_mfma_f32_16x16x32_bf16(a1, b1v, acc[1][1], 0, 0, 0);
    __builtin_amdgcn_s_setprio(0);
  }
#undef ISSUE_SLOT
  __syncthreads();  // all waves done reading h1

  // epilogue: h2 -> h_lds (C layout: row=gg*4+r, col=ml)
#pragma unroll
  for (int nt = 0; nt < 2; ++nt) {
    const int col = (ct0 + nt) * 16 + ml;
    const float bias = b2[col];
#pragma unroll
    for (int mt = 0; mt < 2; ++mt) {
#pragma unroll
      for (int r = 0; r < 4; ++r) {
        const int row = mt * 16 + gg * 4 + r;
        h_lds[row * 512 + (col ^ ((row & 15) << 3))] =
            f2bf(fast_tanh(acc[mt][nt][r] + bias));
      }
    }
  }
  __syncthreads();

  // ---- Phase B3: logits partials, all 16 waves (2 MFMA each) ----
  {
    const int kc = wv >> 1;  // k-chunk 0..7 (k = kc*64 .. kc*64+63)
    const int rh = wv & 1;   // row half
    f32x4 a3 = (f32x4){0.f, 0.f, 0.f, 0.f};
    const short8* B3p = (const short8*)W3F;
#pragma unroll
    for (int j = 0; j < 2; ++j) {
      const int ks = kc * 2 + j;
      const int k = ks * 32 + gg * 8;
      const short8 a =
          *(const short8*)(&h_lds[(rh * 16 + ml) * 512 + (k ^ aswz)]);
      const short8 bb = B3p[ks * 64 + lane];
      a3 = __builtin_amdgcn_mfma_f32_16x16x32_bf16(a, bb, a3, 0, 0, 0);
    }
    if (ml < 5) {
#pragma unroll
      for (int r = 0; r < 4; ++r)
        part_lds[kc][rh * 16 + gg * 4 + r][ml] = a3[r];
    }
  }
  __syncthreads();

  // ---- Phase B4: softmax, reward, flux, outputs ----
  if (tid < 32) {
    const int r = tid;
    const int n = n0 + r;
    float lg[5];
#pragma unroll
    for (int s = 0; s < 5; ++s) {
      float a = b3[s];
#pragma unroll
      for (int kc = 0; kc < 8; ++kc) a += part_lds[kc][r][s];
      lg[s] = a;
    }
    const float m =
        fmaxf(fmaxf(fmaxf(lg[0], lg[1]), fmaxf(lg[2], lg[3])), lg[4]);
    float e[5], sum = 0.f;
#pragma unroll
    for (int s = 0; s < 5; ++s) {
      e[s] = __expf(lg[s] - m);
      sum += e[s];
    }
    const float inv = 1.f / sum;
    float w[5], rw = 0.f;
#pragma unroll
    for (int s = 0; s < 5; ++s) {
      w[s] = e[s] * inv;
      rw += w[s] * w[s];
    }
    float* ap = actions_out + ((size_t)b * NN + n) * SS;
#pragma unroll
    for (int s = 0; s < 5; ++s) __builtin_nontemporal_store(w[s], ap + s);
    __builtin_nontemporal_store(-rw, rewards_out + b * NN + n);
#pragma unroll
    for (int v = 0; v < VV; ++v) {
      float fx = 0.f;
#pragma unroll
      for (int s = 0; s < 5; ++s) fx += u_lds[v][r + s] * w[s];
      flux_out[(b * VV + v) * NN + n] = fx;
    }
  }
}

// ---------------- epilogue: u_32 -> states[31] ----------------
__global__ void final_update(const float* __restrict__ u_prev,
                             const float* __restrict__ flux_prev,
                             float* __restrict__ states_out) {
  const int idx = blockIdx.x * 256 + threadIdx.x;
  if (idx < BB * VV * NN) {
    const int n = idx & (NN - 1);
    const int base = idx - n;
    const int nm = (n - 1) & (NN - 1);
    states_out[idx] =
        u_prev[idx] - DTDX * (flux_prev[idx] - flux_prev[base + nm]);
  }
}

extern "C" void kernel_launch(void* const* d_in, const int* in_sizes, int n_in,
                              void* d_out, int out_size, void* d_ws,
                              size_t ws_size, hipStream_t stream) {
  const float* u0 = (const float*)d_in[0];
  const float* W1 = (const float*)d_in[1];
  const float* b1 = (const float*)d_in[2];
  const float* W2 = (const float*)d_in[3];
  const float* b2 = (const float*)d_in[4];
  const float* W3 = (const float*)d_in[5];
  const float* b3 = (const float*)d_in[6];

  float* states = (float*)d_out;                         // [32,16,3,512]
  float* actions = states + (size_t)TT * BB * VV * NN;   // [32,16,512,5]
  float* rewards = actions + (size_t)TT * BB * NN * SS;  // [32,16,512]

  char* ws = (char*)d_ws;
  float* ubuf[2] = {(float*)ws, (float*)(ws + 98304)};
  float* fbuf[2] = {(float*)(ws + 2 * 98304), (float*)(ws + 3 * 98304)};
  short* W1F = (short*)(ws + 4 * 98304);                   // 32 KB
  short* W2F = (short*)(ws + 4 * 98304 + 32768);           // 512 KB
  short* W3F = (short*)(ws + 4 * 98304 + 32768 + 524288);  // 16 KB

  init_repack<<<dim3(133), dim3(256), 0, stream>>>(W1, b1, W2, W3, W1F, W2F,
                                                   W3F);

  for (int t = 0; t < TT; ++t) {
    if (t == 0) {
      step_kernel<true><<<dim3(256), dim3(1024), 0, stream>>>(
          u0, (const float*)nullptr, W1F, W2F, b2, W3F, b3, (float*)nullptr,
          (float*)nullptr, fbuf[0], actions, rewards);
    } else {
      const float* up = (t == 1) ? u0 : ubuf[(t - 1) & 1];
      step_kernel<false><<<dim3(256), dim3(1024), 0, stream>>>(
          up, fbuf[(t - 1) & 1], W1F, W2F, b2, W3F, b3, ubuf[t & 1],
          states + (size_t)(t - 1) * BB * VV * NN, fbuf[t & 1],
          actions + (size_t)t * BB * NN * SS, rewards + (size_t)t * BB * NN);
    }
  }
  final_update<<<dim3((BB * VV * NN + 255) / 256), dim3(256), 0, stream>>>(
      ubuf[1], fbuf[1], states + (size_t)(TT - 1) * BB * VV * NN);
}